// Round 1
// baseline (2970.027 us; speedup 1.0000x reference)
//
#include <hip/hip_runtime.h>

#define N_NODES   100000
#define N_EDGES   3200000
#define F_IN      256
#define HID       16
#define NCLS      40

// ---------------- degree ----------------
__global__ void deg_kernel(const int* __restrict__ ei, int* __restrict__ deg) {
    int e = blockIdx.x * blockDim.x + threadIdx.x;
    if (e < N_EDGES) atomicAdd(&deg[ei[N_EDGES + e]], 1);
}

__global__ void dinv_kernel(const int* __restrict__ deg, float* __restrict__ dinv) {
    int i = blockIdx.x * blockDim.x + threadIdx.x;
    if (i < N_NODES) dinv[i] = rsqrtf((float)(deg[i] + 1));  // +1 self-loop
}

// ---------------- layer-1 GEMM: y1[n,h] = dinv[n] * sum_k x[n,k]*W1[k,h] ----------------
__global__ __launch_bounds__(256) void gemm1_kernel(const float* __restrict__ x,
                                                    const float* __restrict__ W1,
                                                    const float* __restrict__ dinv,
                                                    float* __restrict__ y1) {
    __shared__ float W1s[F_IN * HID];
    int t = threadIdx.x;
    #pragma unroll
    for (int i = 0; i < (F_IN * HID) / 256; i++) W1s[t + i * 256] = W1[t + i * 256];
    __syncthreads();

    int n = blockIdx.x * 256 + t;
    if (n >= N_NODES) return;

    const float4* xr = (const float4*)(x + (size_t)n * F_IN);
    float acc[HID];
    #pragma unroll
    for (int h = 0; h < HID; h++) acc[h] = 0.f;

    #pragma unroll 4
    for (int k4 = 0; k4 < F_IN / 4; k4++) {
        float4 xv = xr[k4];
        int k = k4 * 4;
        #pragma unroll
        for (int h = 0; h < HID; h++) {
            acc[h] += xv.x * W1s[(k + 0) * HID + h] + xv.y * W1s[(k + 1) * HID + h]
                    + xv.z * W1s[(k + 2) * HID + h] + xv.w * W1s[(k + 3) * HID + h];
        }
    }
    float dv = dinv[n];
    float4* o = (float4*)(y1 + (size_t)n * HID);
    #pragma unroll
    for (int q = 0; q < 4; q++)
        o[q] = make_float4(acc[4*q]*dv, acc[4*q+1]*dv, acc[4*q+2]*dv, acc[4*q+3]*dv);
}

// ---------------- scatter 1: agg1[dst,:] += y1[src,:] (16 f32 per edge) ----------------
__global__ void scatter1_kernel(const int* __restrict__ ei, const float* __restrict__ y1,
                                float* __restrict__ agg1) {
    int idx = blockIdx.x * blockDim.x + threadIdx.x;   // (edge, quad)
    if (idx >= N_EDGES * 4) return;
    int e = idx >> 2, q = idx & 3;
    int s = ei[e], d = ei[N_EDGES + e];
    float4 v = *(const float4*)(y1 + (size_t)s * HID + q * 4);
    float* a = agg1 + (size_t)d * HID + q * 4;
    atomicAdd(a + 0, v.x); atomicAdd(a + 1, v.y);
    atomicAdd(a + 2, v.z); atomicAdd(a + 3, v.w);
}

// ---------------- h1 = relu(dinv*(y1+agg1)+b1), in place over agg1 ----------------
__global__ void h1_kernel(const float* __restrict__ y1, const float* __restrict__ b1,
                          const float* __restrict__ dinv, float* __restrict__ agg1) {
    int idx = blockIdx.x * blockDim.x + threadIdx.x;   // (node, quad)
    if (idx >= N_NODES * 4) return;
    int n = idx >> 2, q = idx & 3;
    float dv = dinv[n];
    float4 yv = *(const float4*)(y1 + (size_t)n * HID + q * 4);
    float4 av = *(const float4*)(agg1 + (size_t)n * HID + q * 4);
    float4 r;
    r.x = fmaxf(dv * (yv.x + av.x) + b1[q * 4 + 0], 0.f);
    r.y = fmaxf(dv * (yv.y + av.y) + b1[q * 4 + 1], 0.f);
    r.z = fmaxf(dv * (yv.z + av.z) + b1[q * 4 + 2], 0.f);
    r.w = fmaxf(dv * (yv.w + av.w) + b1[q * 4 + 3], 0.f);
    *(float4*)(agg1 + (size_t)n * HID + q * 4) = r;
}

// ---------------- layer-2 GEMM: y2[n,c] = dinv[n] * sum_h h1[n,h]*W2[h,c] ----------------
__global__ __launch_bounds__(320) void gemm2_kernel(const float* __restrict__ h1,
                                                    const float* __restrict__ W2,
                                                    const float* __restrict__ dinv,
                                                    float* __restrict__ y2) {
    __shared__ float W2s[HID * NCLS];   // 640
    __shared__ float h1s[8 * HID];      // 128
    int t = threadIdx.x;
    for (int i = t; i < HID * NCLS; i += 320) W2s[i] = W2[i];
    int n0 = blockIdx.x * 8;
    if (t < 8 * HID) {
        int n = n0 + t / HID;
        h1s[t] = (n < N_NODES) ? h1[(size_t)n * HID + (t % HID)] : 0.f;
    }
    __syncthreads();
    int ln = t / NCLS, c = t % NCLS;
    int n = n0 + ln;
    if (ln >= 8 || n >= N_NODES) return;
    float s = 0.f;
    #pragma unroll
    for (int h = 0; h < HID; h++) s += h1s[ln * HID + h] * W2s[h * NCLS + c];
    y2[(size_t)n * NCLS + c] = dinv[n] * s;
}

// ---------------- scatter 2: agg2[dst,:] += y2[src,:] (40 f32 per edge) ----------------
__global__ void scatter2_kernel(const int* __restrict__ ei, const float* __restrict__ y2,
                                float* __restrict__ agg2) {
    int idx = blockIdx.x * blockDim.x + threadIdx.x;   // (edge, tenth)
    if (idx >= N_EDGES * 10) return;
    int e = idx / 10, q = idx - e * 10;
    int s = ei[e], d = ei[N_EDGES + e];
    float4 v = *(const float4*)(y2 + (size_t)s * NCLS + q * 4);
    float* a = agg2 + (size_t)d * NCLS + q * 4;
    atomicAdd(a + 0, v.x); atomicAdd(a + 1, v.y);
    atomicAdd(a + 2, v.z); atomicAdd(a + 3, v.w);
}

// ---------------- epilogue: out = dinv*(y2+agg2)+b2 ----------------
__global__ void out_kernel(const float* __restrict__ y2, const float* __restrict__ agg2,
                           const float* __restrict__ b2, const float* __restrict__ dinv,
                           float* __restrict__ out) {
    int idx = blockIdx.x * blockDim.x + threadIdx.x;   // (node, tenth)
    if (idx >= N_NODES * 10) return;
    int n = idx / 10, q = idx - n * 10;
    float dv = dinv[n];
    float4 yv = *(const float4*)(y2 + (size_t)n * NCLS + q * 4);
    float4 av = *(const float4*)(agg2 + (size_t)n * NCLS + q * 4);
    float4 r;
    r.x = dv * (yv.x + av.x) + b2[q * 4 + 0];
    r.y = dv * (yv.y + av.y) + b2[q * 4 + 1];
    r.z = dv * (yv.z + av.z) + b2[q * 4 + 2];
    r.w = dv * (yv.w + av.w) + b2[q * 4 + 3];
    *(float4*)(out + (size_t)n * NCLS + q * 4) = r;
}

extern "C" void kernel_launch(void* const* d_in, const int* in_sizes, int n_in,
                              void* d_out, int out_size, void* d_ws, size_t ws_size,
                              hipStream_t stream) {
    const float* x   = (const float*)d_in[0];
    const int*   ei  = (const int*)  d_in[1];   // [2, E] int32
    const float* W1  = (const float*)d_in[2];
    const float* b1  = (const float*)d_in[3];
    const float* W2  = (const float*)d_in[4];
    const float* b2  = (const float*)d_in[5];
    float* out = (float*)d_out;

    char* ws = (char*)d_ws;
    int*   deg  = (int*)  (ws + 0);                       //  0.4 MB
    float* dinv = (float*)(ws + 400000);                  //  0.4 MB
    float* y1   = (float*)(ws + 800000);                  //  6.4 MB
    float* agg1 = (float*)(ws + 800000 + 6400000);        //  6.4 MB (reused as h1)
    float* y2   = (float*)(ws + 800000 + 12800000);       // 16.0 MB
    float* agg2 = (float*)(ws + 800000 + 12800000 + 16000000); // 16.0 MB  (total 45.6 MB)

    hipMemsetAsync(deg,  0, (size_t)N_NODES * 4, stream);
    hipMemsetAsync(agg1, 0, (size_t)N_NODES * HID * 4, stream);
    hipMemsetAsync(agg2, 0, (size_t)N_NODES * NCLS * 4, stream);

    deg_kernel<<<(N_EDGES + 255) / 256, 256, 0, stream>>>(ei, deg);
    dinv_kernel<<<(N_NODES + 255) / 256, 256, 0, stream>>>(deg, dinv);
    gemm1_kernel<<<(N_NODES + 255) / 256, 256, 0, stream>>>(x, W1, dinv, y1);
    scatter1_kernel<<<(N_EDGES * 4 + 255) / 256, 256, 0, stream>>>(ei, y1, agg1);
    h1_kernel<<<(N_NODES * 4 + 255) / 256, 256, 0, stream>>>(y1, b1, dinv, agg1);
    gemm2_kernel<<<(N_NODES + 7) / 8, 320, 0, stream>>>(agg1, W2, dinv, y2);
    scatter2_kernel<<<(N_EDGES * 10 + 255) / 256, 256, 0, stream>>>(ei, y2, agg2);
    out_kernel<<<(N_NODES * 10 + 255) / 256, 256, 0, stream>>>(y2, agg2, b2, dinv, out);
}

// Round 2
// 823.700 us; speedup vs baseline: 3.6057x; 3.6057x over previous
//
#include <hip/hip_runtime.h>

#define N_NODES   100000
#define N_EDGES   3200000
#define F_IN      256
#define HID       16
#define NCLS      40

// ---------------- degree (in-degree of dst, before self-loop) ----------------
__global__ void deg_kernel(const int* __restrict__ ei, int* __restrict__ deg) {
    int e = blockIdx.x * blockDim.x + threadIdx.x;
    if (e < N_EDGES) atomicAdd(&deg[ei[N_EDGES + e]], 1);
}

__global__ void dinv_kernel(const int* __restrict__ deg, float* __restrict__ dinv) {
    int i = blockIdx.x * blockDim.x + threadIdx.x;
    if (i < N_NODES) dinv[i] = rsqrtf((float)(deg[i] + 1));  // +1 self-loop
}

// ---------------- exclusive scan of deg -> rowptr (single block) ----------------
__global__ __launch_bounds__(1024) void scan_kernel(const int* __restrict__ deg,
                                                    int* __restrict__ rowptr) {
    __shared__ int part[1024];
    const int CH = (N_NODES + 1023) / 1024;  // 98 nodes per thread
    int t = threadIdx.x;
    int base = t * CH;
    int sum = 0;
    for (int i = 0; i < CH; i++) {
        int n = base + i;
        if (n < N_NODES) sum += deg[n];
    }
    part[t] = sum;
    __syncthreads();
    // Hillis-Steele inclusive scan
    for (int off = 1; off < 1024; off <<= 1) {
        int v = (t >= off) ? part[t - off] : 0;
        __syncthreads();
        part[t] += v;
        __syncthreads();
    }
    int run = (t == 0) ? 0 : part[t - 1];
    for (int i = 0; i < CH; i++) {
        int n = base + i;
        if (n < N_NODES) { rowptr[n] = run; run += deg[n]; }
    }
    if (t == 1023) rowptr[N_NODES] = run;  // == N_EDGES
}

// ---------------- bucket-fill: csr_src sorted by dst ----------------
__global__ void fill_kernel(const int* __restrict__ ei, const int* __restrict__ rowptr,
                            int* __restrict__ cursor, int* __restrict__ csr_src) {
    int e = blockIdx.x * blockDim.x + threadIdx.x;
    if (e >= N_EDGES) return;
    int d = ei[N_EDGES + e];
    int pos = atomicAdd(&cursor[d], 1);
    csr_src[rowptr[d] + pos] = ei[e];
}

// ---------------- layer-1 GEMM: y1[n,h] = dinv[n] * sum_k x[n,k]*W1[k,h] ----------------
__global__ __launch_bounds__(256) void gemm1_kernel(const float* __restrict__ x,
                                                    const float* __restrict__ W1,
                                                    const float* __restrict__ dinv,
                                                    float* __restrict__ y1) {
    __shared__ float W1s[F_IN * HID];
    int t = threadIdx.x;
    #pragma unroll
    for (int i = 0; i < (F_IN * HID) / 256; i++) W1s[t + i * 256] = W1[t + i * 256];
    __syncthreads();

    int n = blockIdx.x * 256 + t;
    if (n >= N_NODES) return;

    const float4* xr = (const float4*)(x + (size_t)n * F_IN);
    float acc[HID];
    #pragma unroll
    for (int h = 0; h < HID; h++) acc[h] = 0.f;

    #pragma unroll 4
    for (int k4 = 0; k4 < F_IN / 4; k4++) {
        float4 xv = xr[k4];
        int k = k4 * 4;
        #pragma unroll
        for (int h = 0; h < HID; h++) {
            acc[h] += xv.x * W1s[(k + 0) * HID + h] + xv.y * W1s[(k + 1) * HID + h]
                    + xv.z * W1s[(k + 2) * HID + h] + xv.w * W1s[(k + 3) * HID + h];
        }
    }
    float dv = dinv[n];
    float4* o = (float4*)(y1 + (size_t)n * HID);
    #pragma unroll
    for (int q = 0; q < 4; q++)
        o[q] = make_float4(acc[4*q]*dv, acc[4*q+1]*dv, acc[4*q+2]*dv, acc[4*q+3]*dv);
}

// ---------------- gather 1: h1 = relu(dinv*(y1[n] + sum_src y1[src]) + b1) ----------------
__global__ void gather1_kernel(const int* __restrict__ rowptr, const int* __restrict__ csr_src,
                               const float* __restrict__ y1, const float* __restrict__ b1,
                               const float* __restrict__ dinv, float* __restrict__ h1) {
    int idx = blockIdx.x * blockDim.x + threadIdx.x;  // (node, quad)
    if (idx >= N_NODES * 4) return;
    int n = idx >> 2, q = idx & 3;
    int beg = rowptr[n], end = rowptr[n + 1];
    float4 acc = *(const float4*)(y1 + (size_t)n * HID + q * 4);  // self-loop
    int e = beg;
    for (; e + 1 < end; e += 2) {
        int s0 = csr_src[e], s1 = csr_src[e + 1];
        float4 v0 = *(const float4*)(y1 + (size_t)s0 * HID + q * 4);
        float4 v1 = *(const float4*)(y1 + (size_t)s1 * HID + q * 4);
        acc.x += v0.x + v1.x; acc.y += v0.y + v1.y;
        acc.z += v0.z + v1.z; acc.w += v0.w + v1.w;
    }
    if (e < end) {
        int s = csr_src[e];
        float4 v = *(const float4*)(y1 + (size_t)s * HID + q * 4);
        acc.x += v.x; acc.y += v.y; acc.z += v.z; acc.w += v.w;
    }
    float dv = dinv[n];
    float4 r;
    r.x = fmaxf(dv * acc.x + b1[q * 4 + 0], 0.f);
    r.y = fmaxf(dv * acc.y + b1[q * 4 + 1], 0.f);
    r.z = fmaxf(dv * acc.z + b1[q * 4 + 2], 0.f);
    r.w = fmaxf(dv * acc.w + b1[q * 4 + 3], 0.f);
    *(float4*)(h1 + (size_t)n * HID + q * 4) = r;
}

// ---------------- layer-2 GEMM: y2[n,c] = dinv[n] * sum_h h1[n,h]*W2[h,c] ----------------
__global__ __launch_bounds__(320) void gemm2_kernel(const float* __restrict__ h1,
                                                    const float* __restrict__ W2,
                                                    const float* __restrict__ dinv,
                                                    float* __restrict__ y2) {
    __shared__ float W2s[HID * NCLS];   // 640
    __shared__ float h1s[8 * HID];      // 128
    int t = threadIdx.x;
    for (int i = t; i < HID * NCLS; i += 320) W2s[i] = W2[i];
    int n0 = blockIdx.x * 8;
    if (t < 8 * HID) {
        int n = n0 + t / HID;
        h1s[t] = (n < N_NODES) ? h1[(size_t)n * HID + (t % HID)] : 0.f;
    }
    __syncthreads();
    int ln = t / NCLS, c = t % NCLS;
    int n = n0 + ln;
    if (ln >= 8 || n >= N_NODES) return;
    float s = 0.f;
    #pragma unroll
    for (int h = 0; h < HID; h++) s += h1s[ln * HID + h] * W2s[h * NCLS + c];
    y2[(size_t)n * NCLS + c] = dinv[n] * s;
}

// ---------------- gather 2: out = dinv*(y2[n] + sum_src y2[src]) + b2 ----------------
__global__ void gather2_kernel(const int* __restrict__ rowptr, const int* __restrict__ csr_src,
                               const float* __restrict__ y2, const float* __restrict__ b2,
                               const float* __restrict__ dinv, float* __restrict__ out) {
    int idx = blockIdx.x * blockDim.x + threadIdx.x;  // (node, tenth)
    if (idx >= N_NODES * 10) return;
    int n = idx / 10, q = idx - n * 10;
    int beg = rowptr[n], end = rowptr[n + 1];
    float4 acc = *(const float4*)(y2 + (size_t)n * NCLS + q * 4);  // self-loop
    int e = beg;
    for (; e + 1 < end; e += 2) {
        int s0 = csr_src[e], s1 = csr_src[e + 1];
        float4 v0 = *(const float4*)(y2 + (size_t)s0 * NCLS + q * 4);
        float4 v1 = *(const float4*)(y2 + (size_t)s1 * NCLS + q * 4);
        acc.x += v0.x + v1.x; acc.y += v0.y + v1.y;
        acc.z += v0.z + v1.z; acc.w += v0.w + v1.w;
    }
    if (e < end) {
        int s = csr_src[e];
        float4 v = *(const float4*)(y2 + (size_t)s * NCLS + q * 4);
        acc.x += v.x; acc.y += v.y; acc.z += v.z; acc.w += v.w;
    }
    float dv = dinv[n];
    float4 r;
    r.x = dv * acc.x + b2[q * 4 + 0];
    r.y = dv * acc.y + b2[q * 4 + 1];
    r.z = dv * acc.z + b2[q * 4 + 2];
    r.w = dv * acc.w + b2[q * 4 + 3];
    *(float4*)(out + (size_t)n * NCLS + q * 4) = r;
}

extern "C" void kernel_launch(void* const* d_in, const int* in_sizes, int n_in,
                              void* d_out, int out_size, void* d_ws, size_t ws_size,
                              hipStream_t stream) {
    const float* x   = (const float*)d_in[0];
    const int*   ei  = (const int*)  d_in[1];   // [2, E] int32
    const float* W1  = (const float*)d_in[2];
    const float* b1  = (const float*)d_in[3];
    const float* W2  = (const float*)d_in[4];
    const float* b2  = (const float*)d_in[5];
    float* out = (float*)d_out;

    char* ws = (char*)d_ws;
    size_t off = 0;
    int*   deg     = (int*)  (ws + off); off += (size_t)N_NODES * 4;            // 0.4 MB
    float* dinv    = (float*)(ws + off); off += (size_t)N_NODES * 4;            // 0.4 MB
    int*   rowptr  = (int*)  (ws + off); off += (size_t)(N_NODES + 1) * 4 + 60; // 0.4 MB (pad to 16B)
    off &= ~(size_t)15;
    int*   cursor  = (int*)  (ws + off); off += (size_t)N_NODES * 4;            // 0.4 MB
    int*   csr_src = (int*)  (ws + off); off += (size_t)N_EDGES * 4;            // 12.8 MB
    float* y1      = (float*)(ws + off); off += (size_t)N_NODES * HID * 4;      // 6.4 MB
    float* h1      = (float*)(ws + off); off += (size_t)N_NODES * HID * 4;      // 6.4 MB
    float* y2      = (float*)(ws + off); off += (size_t)N_NODES * NCLS * 4;     // 16.0 MB

    hipMemsetAsync(deg,    0, (size_t)N_NODES * 4, stream);
    hipMemsetAsync(cursor, 0, (size_t)N_NODES * 4, stream);

    deg_kernel <<<(N_EDGES + 255) / 256, 256, 0, stream>>>(ei, deg);
    dinv_kernel<<<(N_NODES + 255) / 256, 256, 0, stream>>>(deg, dinv);
    scan_kernel<<<1, 1024, 0, stream>>>(deg, rowptr);
    fill_kernel<<<(N_EDGES + 255) / 256, 256, 0, stream>>>(ei, rowptr, cursor, csr_src);

    gemm1_kernel  <<<(N_NODES + 255) / 256, 256, 0, stream>>>(x, W1, dinv, y1);
    gather1_kernel<<<(N_NODES * 4 + 255) / 256, 256, 0, stream>>>(rowptr, csr_src, y1, b1, dinv, h1);
    gemm2_kernel  <<<(N_NODES + 7) / 8, 320, 0, stream>>>(h1, W2, dinv, y2);
    gather2_kernel<<<(N_NODES * 10 + 255) / 256, 256, 0, stream>>>(rowptr, csr_src, y2, b2, dinv, out);
}

// Round 3
// 670.188 us; speedup vs baseline: 4.4316x; 1.2291x over previous
//
#include <hip/hip_runtime.h>

#define N_NODES   100000
#define N_EDGES   3200000
#define F_IN      256
#define HID       16
#define NCLS      40

#define SCAN_B    1024
#define SCAN_NB   ((N_NODES + SCAN_B - 1) / SCAN_B)   // 98 blocks

// ---------------- degree (in-degree of dst, before self-loop) ----------------
__global__ void deg_kernel(const int* __restrict__ ei, int* __restrict__ deg) {
    int e = blockIdx.x * blockDim.x + threadIdx.x;
    if (e < N_EDGES) atomicAdd(&deg[ei[N_EDGES + e]], 1);
}

__global__ void dinv_kernel(const int* __restrict__ deg, float* __restrict__ dinv) {
    int i = blockIdx.x * blockDim.x + threadIdx.x;
    if (i < N_NODES) dinv[i] = rsqrtf((float)(deg[i] + 1));  // +1 self-loop
}

// ---------------- scan phase A: per-block sums ----------------
__global__ __launch_bounds__(SCAN_B) void scan_partial_kernel(const int* __restrict__ deg,
                                                              int* __restrict__ bsum) {
    __shared__ int red[SCAN_B];
    int t = threadIdx.x;
    int i = blockIdx.x * SCAN_B + t;
    red[t] = (i < N_NODES) ? deg[i] : 0;
    __syncthreads();
    for (int off = SCAN_B / 2; off > 0; off >>= 1) {
        if (t < off) red[t] += red[t + off];
        __syncthreads();
    }
    if (t == 0) bsum[blockIdx.x] = red[0];
}

// ---------------- scan phase B: exclusive scan of 98 block sums ----------------
__global__ __launch_bounds__(128) void scan_bsums_kernel(const int* __restrict__ bsum,
                                                         int* __restrict__ boff) {
    __shared__ int part[128];
    int t = threadIdx.x;
    part[t] = (t < SCAN_NB) ? bsum[t] : 0;
    __syncthreads();
    for (int off = 1; off < 128; off <<= 1) {
        int v = (t >= off) ? part[t - off] : 0;
        __syncthreads();
        part[t] += v;
        __syncthreads();
    }
    if (t < SCAN_NB) boff[t] = (t == 0) ? 0 : part[t - 1];
}

// ---------------- scan phase C: in-block exclusive scan + offset -> rowptr ----------------
__global__ __launch_bounds__(SCAN_B) void scan_final_kernel(const int* __restrict__ deg,
                                                            const int* __restrict__ boff,
                                                            int* __restrict__ rowptr) {
    __shared__ int part[SCAN_B];
    int t = threadIdx.x;
    int i = blockIdx.x * SCAN_B + t;
    int v = (i < N_NODES) ? deg[i] : 0;
    part[t] = v;
    __syncthreads();
    for (int off = 1; off < SCAN_B; off <<= 1) {
        int p = (t >= off) ? part[t - off] : 0;
        __syncthreads();
        part[t] += p;
        __syncthreads();
    }
    if (i < N_NODES) rowptr[i] = boff[blockIdx.x] + part[t] - v;  // exclusive
    if (i == 0) rowptr[N_NODES] = N_EDGES;
}

// ---------------- bucket-fill: csr_src sorted by dst ----------------
__global__ void fill_kernel(const int* __restrict__ ei, const int* __restrict__ rowptr,
                            int* __restrict__ cursor, int* __restrict__ csr_src) {
    int e = blockIdx.x * blockDim.x + threadIdx.x;
    if (e >= N_EDGES) return;
    int d = ei[N_EDGES + e];
    int pos = atomicAdd(&cursor[d], 1);
    csr_src[rowptr[d] + pos] = ei[e];
}

// ---------------- layer-1 GEMM: y1[n,h] = dinv[n] * sum_k x[n,k]*W1[k,h] ----------------
__global__ __launch_bounds__(256) void gemm1_kernel(const float* __restrict__ x,
                                                    const float* __restrict__ W1,
                                                    const float* __restrict__ dinv,
                                                    float* __restrict__ y1) {
    __shared__ float W1s[F_IN * HID];
    int t = threadIdx.x;
    #pragma unroll
    for (int i = 0; i < (F_IN * HID) / 256; i++) W1s[t + i * 256] = W1[t + i * 256];
    __syncthreads();

    int n = blockIdx.x * 256 + t;
    if (n >= N_NODES) return;

    const float4* xr = (const float4*)(x + (size_t)n * F_IN);
    float acc[HID];
    #pragma unroll
    for (int h = 0; h < HID; h++) acc[h] = 0.f;

    #pragma unroll 4
    for (int k4 = 0; k4 < F_IN / 4; k4++) {
        float4 xv = xr[k4];
        int k = k4 * 4;
        #pragma unroll
        for (int h = 0; h < HID; h++) {
            acc[h] += xv.x * W1s[(k + 0) * HID + h] + xv.y * W1s[(k + 1) * HID + h]
                    + xv.z * W1s[(k + 2) * HID + h] + xv.w * W1s[(k + 3) * HID + h];
        }
    }
    float dv = dinv[n];
    float4* o = (float4*)(y1 + (size_t)n * HID);
    #pragma unroll
    for (int q = 0; q < 4; q++)
        o[q] = make_float4(acc[4*q]*dv, acc[4*q+1]*dv, acc[4*q+2]*dv, acc[4*q+3]*dv);
}

// ---------------- gather 1: h1 = relu(dinv*(y1[n] + sum_src y1[src]) + b1) ----------------
__global__ void gather1_kernel(const int* __restrict__ rowptr, const int* __restrict__ csr_src,
                               const float* __restrict__ y1, const float* __restrict__ b1,
                               const float* __restrict__ dinv, float* __restrict__ h1) {
    int idx = blockIdx.x * blockDim.x + threadIdx.x;  // (node, quad)
    if (idx >= N_NODES * 4) return;
    int n = idx >> 2, q = idx & 3;
    int beg = rowptr[n], end = rowptr[n + 1];
    float4 acc = *(const float4*)(y1 + (size_t)n * HID + q * 4);  // self-loop
    int e = beg;
    for (; e + 1 < end; e += 2) {
        int s0 = csr_src[e], s1 = csr_src[e + 1];
        float4 v0 = *(const float4*)(y1 + (size_t)s0 * HID + q * 4);
        float4 v1 = *(const float4*)(y1 + (size_t)s1 * HID + q * 4);
        acc.x += v0.x + v1.x; acc.y += v0.y + v1.y;
        acc.z += v0.z + v1.z; acc.w += v0.w + v1.w;
    }
    if (e < end) {
        int s = csr_src[e];
        float4 v = *(const float4*)(y1 + (size_t)s * HID + q * 4);
        acc.x += v.x; acc.y += v.y; acc.z += v.z; acc.w += v.w;
    }
    float dv = dinv[n];
    float4 r;
    r.x = fmaxf(dv * acc.x + b1[q * 4 + 0], 0.f);
    r.y = fmaxf(dv * acc.y + b1[q * 4 + 1], 0.f);
    r.z = fmaxf(dv * acc.z + b1[q * 4 + 2], 0.f);
    r.w = fmaxf(dv * acc.w + b1[q * 4 + 3], 0.f);
    *(float4*)(h1 + (size_t)n * HID + q * 4) = r;
}

// ---------------- layer-2 GEMM: y2[n,c] = dinv[n] * sum_h h1[n,h]*W2[h,c] ----------------
__global__ __launch_bounds__(320) void gemm2_kernel(const float* __restrict__ h1,
                                                    const float* __restrict__ W2,
                                                    const float* __restrict__ dinv,
                                                    float* __restrict__ y2) {
    __shared__ float W2s[HID * NCLS];   // 640
    __shared__ float h1s[8 * HID];      // 128
    int t = threadIdx.x;
    for (int i = t; i < HID * NCLS; i += 320) W2s[i] = W2[i];
    int n0 = blockIdx.x * 8;
    if (t < 8 * HID) {
        int n = n0 + t / HID;
        h1s[t] = (n < N_NODES) ? h1[(size_t)n * HID + (t % HID)] : 0.f;
    }
    __syncthreads();
    int ln = t / NCLS, c = t % NCLS;
    int n = n0 + ln;
    if (ln >= 8 || n >= N_NODES) return;
    float s = 0.f;
    #pragma unroll
    for (int h = 0; h < HID; h++) s += h1s[ln * HID + h] * W2s[h * NCLS + c];
    y2[(size_t)n * NCLS + c] = dinv[n] * s;
}

// ---------------- gather 2: out = dinv*(y2[n] + sum_src y2[src]) + b2 ----------------
__global__ void gather2_kernel(const int* __restrict__ rowptr, const int* __restrict__ csr_src,
                               const float* __restrict__ y2, const float* __restrict__ b2,
                               const float* __restrict__ dinv, float* __restrict__ out) {
    int idx = blockIdx.x * blockDim.x + threadIdx.x;  // (node, tenth)
    if (idx >= N_NODES * 10) return;
    int n = idx / 10, q = idx - n * 10;
    int beg = rowptr[n], end = rowptr[n + 1];
    float4 acc = *(const float4*)(y2 + (size_t)n * NCLS + q * 4);  // self-loop
    int e = beg;
    for (; e + 1 < end; e += 2) {
        int s0 = csr_src[e], s1 = csr_src[e + 1];
        float4 v0 = *(const float4*)(y2 + (size_t)s0 * NCLS + q * 4);
        float4 v1 = *(const float4*)(y2 + (size_t)s1 * NCLS + q * 4);
        acc.x += v0.x + v1.x; acc.y += v0.y + v1.y;
        acc.z += v0.z + v1.z; acc.w += v0.w + v1.w;
    }
    if (e < end) {
        int s = csr_src[e];
        float4 v = *(const float4*)(y2 + (size_t)s * NCLS + q * 4);
        acc.x += v.x; acc.y += v.y; acc.z += v.z; acc.w += v.w;
    }
    float dv = dinv[n];
    float4 r;
    r.x = dv * acc.x + b2[q * 4 + 0];
    r.y = dv * acc.y + b2[q * 4 + 1];
    r.z = dv * acc.z + b2[q * 4 + 2];
    r.w = dv * acc.w + b2[q * 4 + 3];
    *(float4*)(out + (size_t)n * NCLS + q * 4) = r;
}

extern "C" void kernel_launch(void* const* d_in, const int* in_sizes, int n_in,
                              void* d_out, int out_size, void* d_ws, size_t ws_size,
                              hipStream_t stream) {
    const float* x   = (const float*)d_in[0];
    const int*   ei  = (const int*)  d_in[1];   // [2, E] int32
    const float* W1  = (const float*)d_in[2];
    const float* b1  = (const float*)d_in[3];
    const float* W2  = (const float*)d_in[4];
    const float* b2  = (const float*)d_in[5];
    float* out = (float*)d_out;

    char* ws = (char*)d_ws;
    size_t off = 0;
    int*   deg     = (int*)  (ws + off); off += (size_t)N_NODES * 4;            // 0.4 MB
    float* dinv    = (float*)(ws + off); off += (size_t)N_NODES * 4;            // 0.4 MB
    int*   rowptr  = (int*)  (ws + off); off += (size_t)(N_NODES + 1) * 4 + 60; // 0.4 MB
    off &= ~(size_t)15;
    int*   cursor  = (int*)  (ws + off); off += (size_t)N_NODES * 4;            // 0.4 MB
    int*   bsum    = (int*)  (ws + off); off += (size_t)SCAN_NB * 4;
    int*   boff    = (int*)  (ws + off); off += (size_t)SCAN_NB * 4 + 8;
    off = (off + 15) & ~(size_t)15;
    int*   csr_src = (int*)  (ws + off); off += (size_t)N_EDGES * 4;            // 12.8 MB
    float* y1      = (float*)(ws + off); off += (size_t)N_NODES * HID * 4;      // 6.4 MB
    float* h1      = (float*)(ws + off); off += (size_t)N_NODES * HID * 4;      // 6.4 MB
    float* y2      = (float*)(ws + off); off += (size_t)N_NODES * NCLS * 4;     // 16.0 MB

    hipMemsetAsync(deg,    0, (size_t)N_NODES * 4, stream);
    hipMemsetAsync(cursor, 0, (size_t)N_NODES * 4, stream);

    deg_kernel <<<(N_EDGES + 255) / 256, 256, 0, stream>>>(ei, deg);
    dinv_kernel<<<(N_NODES + 255) / 256, 256, 0, stream>>>(deg, dinv);
    scan_partial_kernel<<<SCAN_NB, SCAN_B, 0, stream>>>(deg, bsum);
    scan_bsums_kernel  <<<1, 128, 0, stream>>>(bsum, boff);
    scan_final_kernel  <<<SCAN_NB, SCAN_B, 0, stream>>>(deg, boff, rowptr);
    fill_kernel<<<(N_EDGES + 255) / 256, 256, 0, stream>>>(ei, rowptr, cursor, csr_src);

    gemm1_kernel  <<<(N_NODES + 255) / 256, 256, 0, stream>>>(x, W1, dinv, y1);
    gather1_kernel<<<(N_NODES * 4 + 255) / 256, 256, 0, stream>>>(rowptr, csr_src, y1, b1, dinv, h1);
    gemm2_kernel  <<<(N_NODES + 7) / 8, 320, 0, stream>>>(h1, W2, dinv, y2);
    gather2_kernel<<<(N_NODES * 10 + 255) / 256, 256, 0, stream>>>(rowptr, csr_src, y2, b2, dinv, out);
}